// Round 1
// baseline (41.186 us; speedup 1.0000x reference)
//
#include <hip/hip_runtime.h>
#include <math.h>

// Problem constants (from reference setup_inputs)
#define N_NODES  2048
#define N_GRAPHS 128
#define N_SUB_   32
#define SSIZE    10
#define NPAIRS   45
#define FEAT     96      // N_SUB * (MAX_STEP-1)
#define HIDDEN   128
#define OUTD     2
#define BN_EPS   1e-5f

// ws layout (floats)
#define WS_C1 0
#define WS_C2 2048
#define WS_C3 4096
#define WS_XN 6144   // 128*96 = 12288 floats

// y = A @ x  (A is 2048x2048 row-major, symmetric). ones_flag=1 -> x treated as all-ones.
// One wave (64 lanes) per row, float4 coalesced loads.
__global__ __launch_bounds__(256) void matvec_kernel(const float* __restrict__ A,
                                                     const float* __restrict__ x,
                                                     float* __restrict__ y,
                                                     int ones_flag) {
    const int n = N_NODES;
    int row  = (blockIdx.x * blockDim.x + threadIdx.x) >> 6;
    int lane = threadIdx.x & 63;
    if (row >= n) return;
    const float* Ar = A + (size_t)row * n;
    float sum = 0.f;
    if (ones_flag) {
        for (int c = lane * 4; c < n; c += 256) {
            float4 a = *reinterpret_cast<const float4*>(Ar + c);
            sum += (a.x + a.y) + (a.z + a.w);
        }
    } else {
        for (int c = lane * 4; c < n; c += 256) {
            float4 a  = *reinterpret_cast<const float4*>(Ar + c);
            float4 xv = *reinterpret_cast<const float4*>(x + c);
            sum += a.x * xv.x + a.y * xv.y + a.z * xv.z + a.w * xv.w;
        }
    }
    #pragma unroll
    for (int off = 32; off > 0; off >>= 1) sum += __shfl_down(sum, off);
    if (lane == 0) y[row] = sum;
}

// Single block: segment sums (counts, C_i), subgraph powers (V_i), BatchNorm
// affine coefficients, then write normalized features xn[128][96] to ws.
__global__ __launch_bounds__(256) void fuse_kernel(const int*   __restrict__ gi,
                                                   const float* __restrict__ theta,
                                                   const float* __restrict__ gamma,
                                                   const float* __restrict__ beta,
                                                   const float* __restrict__ c1,
                                                   const float* __restrict__ c2,
                                                   const float* __restrict__ c3,
                                                   float* __restrict__ xn) {
    __shared__ float cnt[N_GRAPHS];
    __shared__ float C[3][N_GRAPHS];
    __shared__ float Vl[3][N_SUB_];
    __shared__ float yl[3][N_GRAPHS];
    __shared__ float my[3], vy[3];
    __shared__ float af[FEAT], bf[FEAT];
    int tid = threadIdx.x;

    if (tid < N_GRAPHS) {
        cnt[tid] = 0.f; C[0][tid] = 0.f; C[1][tid] = 0.f; C[2][tid] = 0.f;
    }
    __syncthreads();

    // segment sums over nodes
    for (int node = tid; node < N_NODES; node += 256) {
        int g = gi[node];
        atomicAdd(&cnt[g], 1.0f);
        atomicAdd(&C[0][g], c1[node]);
        atomicAdd(&C[1][g], c2[node]);
        atomicAdd(&C[2][g], c3[node]);
    }

    // subgraph powers: V_i[s] = 1^T a_sub[s]^i 1
    if (tid < N_SUB_) {
        float a[SSIZE][SSIZE];
        #pragma unroll
        for (int i = 0; i < SSIZE; i++)
            #pragma unroll
            for (int j = 0; j < SSIZE; j++) a[i][j] = 0.f;
        int p = 0;
        #pragma unroll
        for (int i = 0; i < SSIZE; i++) {
            for (int j = i + 1; j < SSIZE; j++) {
                float v = theta[tid * NPAIRS + p];
                v = v > 0.f ? v : 0.f;
                a[i][j] = v; a[j][i] = v;
                p++;
            }
        }
        float u[SSIZE];
        #pragma unroll
        for (int k = 0; k < SSIZE; k++) u[k] = 1.f;
        for (int st = 0; st < 3; st++) {
            float un[SSIZE];
            float V = 0.f;
            #pragma unroll
            for (int k = 0; k < SSIZE; k++) {
                float s = 0.f;
                #pragma unroll
                for (int j = 0; j < SSIZE; j++) s += a[k][j] * u[j];
                un[k] = s; V += s;
            }
            #pragma unroll
            for (int k = 0; k < SSIZE; k++) u[k] = un[k];
            Vl[st][tid] = V;
        }
    }
    __syncthreads();

    // y_i[g] = C_i[g] / counts[g]
    if (tid < N_GRAPHS) {
        float inv = 1.0f / cnt[tid];
        yl[0][tid] = C[0][tid] * inv;
        yl[1][tid] = C[1][tid] * inv;
        yl[2][tid] = C[2][tid] * inv;
    }
    __syncthreads();

    // per-step mean/var of y (two-pass)
    if (tid < 3) {
        float s = 0.f;
        for (int g = 0; g < N_GRAPHS; g++) s += yl[tid][g];
        float m = s * (1.0f / N_GRAPHS);
        float v = 0.f;
        for (int g = 0; g < N_GRAPHS; g++) { float d = yl[tid][g] - m; v += d * d; }
        v *= (1.0f / N_GRAPHS);
        my[tid] = m; vy[tid] = v;
    }
    __syncthreads();

    // BN affine: xn[g][f] = af[f]*y_i[g] + bf[f]
    // x[g][f] = V_f * y_i[g]; mean_f = V_f*my; var_f = V_f^2*vy
    if (tid < FEAT) {
        int i = tid >> 5;      // f/32
        int s = tid & 31;
        float V = Vl[i][s];
        float scale = gamma[tid] * rsqrtf(V * V * vy[i] + BN_EPS);
        af[tid] = scale * V;
        bf[tid] = beta[tid] - scale * V * my[i];
    }
    __syncthreads();

    for (int idx = tid; idx < N_GRAPHS * FEAT; idx += 256) {
        int g = idx / FEAT;
        int f = idx - g * FEAT;
        int i = f >> 5;
        xn[idx] = af[f] * yl[i][g] + bf[f];
    }
}

// One block per graph: h = relu(xn @ w1 + b1); out = h @ w2 + b2
__global__ __launch_bounds__(128) void mlp_kernel(const float* __restrict__ xn,
                                                  const float* __restrict__ w1,
                                                  const float* __restrict__ b1,
                                                  const float* __restrict__ w2,
                                                  const float* __restrict__ b2,
                                                  float* __restrict__ out) {
    int g = blockIdx.x;
    int j = threadIdx.x;
    const float* xr = xn + g * FEAT;
    float acc = b1[j];
    #pragma unroll 8
    for (int f = 0; f < FEAT; f++) acc = fmaf(xr[f], w1[f * HIDDEN + j], acc);
    float h = fmaxf(acc, 0.f);
    float p0 = h * w2[2 * j];
    float p1 = h * w2[2 * j + 1];
    #pragma unroll
    for (int off = 32; off > 0; off >>= 1) {
        p0 += __shfl_down(p0, off);
        p1 += __shfl_down(p1, off);
    }
    __shared__ float red[4];
    int wv = j >> 6, ln = j & 63;
    if (ln == 0) { red[wv * 2] = p0; red[wv * 2 + 1] = p1; }
    __syncthreads();
    if (j == 0) {
        out[2 * g + 0] = red[0] + red[2] + b2[0];
        out[2 * g + 1] = red[1] + red[3] + b2[1];
    }
}

extern "C" void kernel_launch(void* const* d_in, const int* in_sizes, int n_in,
                              void* d_out, int out_size, void* d_ws, size_t ws_size,
                              hipStream_t stream) {
    const float* adj   = (const float*)d_in[0];
    const int*   gi    = (const int*)  d_in[1];
    const float* theta = (const float*)d_in[2];
    const float* gamma = (const float*)d_in[3];
    const float* beta  = (const float*)d_in[4];
    const float* w1    = (const float*)d_in[5];
    const float* b1    = (const float*)d_in[6];
    const float* w2    = (const float*)d_in[7];
    const float* b2    = (const float*)d_in[8];
    float* out = (float*)d_out;
    float* ws  = (float*)d_ws;

    float* c1 = ws + WS_C1;
    float* c2 = ws + WS_C2;
    float* c3 = ws + WS_C3;
    float* xn = ws + WS_XN;

    // c1 = A@1, c2 = A@c1, c3 = A@c2   (colsums of A^i via symmetry)
    matvec_kernel<<<512, 256, 0, stream>>>(adj, nullptr, c1, 1);
    matvec_kernel<<<512, 256, 0, stream>>>(adj, c1, c2, 0);
    matvec_kernel<<<512, 256, 0, stream>>>(adj, c2, c3, 0);

    fuse_kernel<<<1, 256, 0, stream>>>(gi, theta, gamma, beta, c1, c2, c3, xn);

    mlp_kernel<<<N_GRAPHS, HIDDEN, 0, stream>>>(xn, w1, b1, w2, b2, out);
}